// Round 1
// baseline (1785.901 us; speedup 1.0000x reference)
//
#include <hip/hip_runtime.h>
#include <hip/hip_bf16.h>
#include <math.h>

#define S_LEN 2048
#define HID 2048
#define NH 32
#define NKV 8
#define HD 64
#define KVD (NKV * HD)   // 512
#define WINDOW 1024
#define GQA (NH / NKV)   // 4

// ---------------- RoPE tables (f64 precision on device) ----------------
__global__ void rope_table_kernel(float* __restrict__ cosT, float* __restrict__ sinT) {
    int idx = blockIdx.x * blockDim.x + threadIdx.x;  // s*32 + f
    if (idx >= S_LEN * 32) return;
    int s = idx >> 5, f = idx & 31;
    double inv = exp(-2.0 * (double)f / 64.0 * log(500000.0));
    double ang = (double)s * inv;
    cosT[idx] = (float)cos(ang);
    sinT[idx] = (float)sin(ang);
}

// ---------------- generic f32 GEMM: C[M][N] = A[M][K] @ B[K][N] ----------------
// 64x64 tile, 256 threads, 4x4 micro-tile per thread. Dims must be multiples of 64.
__global__ __launch_bounds__(256) void gemm_f32_kernel(const float* __restrict__ A,
                                                       const float* __restrict__ B,
                                                       float* __restrict__ C,
                                                       int M, int N, int K) {
    __shared__ float As[64][65];
    __shared__ float Bs[64][65];
    const int t  = threadIdx.x;
    const int tx = t & 15;       // 0..15
    const int ty = t >> 4;       // 0..15
    const int bm = blockIdx.y * 64;
    const int bn = blockIdx.x * 64;

    float acc[4][4] = {{0.f}};

    for (int k0 = 0; k0 < K; k0 += 64) {
#pragma unroll
        for (int i = 0; i < 4; i++) {
            int r = ty + 16 * i;
            float4 a4 = *reinterpret_cast<const float4*>(&A[(size_t)(bm + r) * K + k0 + tx * 4]);
            As[r][tx * 4 + 0] = a4.x; As[r][tx * 4 + 1] = a4.y;
            As[r][tx * 4 + 2] = a4.z; As[r][tx * 4 + 3] = a4.w;
            float4 b4 = *reinterpret_cast<const float4*>(&B[(size_t)(k0 + r) * N + bn + tx * 4]);
            Bs[r][tx * 4 + 0] = b4.x; Bs[r][tx * 4 + 1] = b4.y;
            Bs[r][tx * 4 + 2] = b4.z; Bs[r][tx * 4 + 3] = b4.w;
        }
        __syncthreads();
#pragma unroll 8
        for (int kk = 0; kk < 64; kk++) {
            float a[4], b[4];
#pragma unroll
            for (int i = 0; i < 4; i++) a[i] = As[ty * 4 + i][kk];
#pragma unroll
            for (int j = 0; j < 4; j++) b[j] = Bs[kk][tx * 4 + j];
#pragma unroll
            for (int i = 0; i < 4; i++)
#pragma unroll
                for (int j = 0; j < 4; j++) acc[i][j] += a[i] * b[j];
        }
        __syncthreads();
    }

#pragma unroll
    for (int i = 0; i < 4; i++) {
        float4 o4 = make_float4(acc[i][0], acc[i][1], acc[i][2], acc[i][3]);
        *reinterpret_cast<float4*>(&C[(size_t)(bm + ty * 4 + i) * N + bn + tx * 4]) = o4;
    }
}

// ---------------- RoPE in-place on Q [S][NH*HD] and K [S][NKV*HD] ----------------
__global__ void rope_kernel(float* __restrict__ Q, float* __restrict__ Kb,
                            const float* __restrict__ cosT, const float* __restrict__ sinT) {
    int idx = blockIdx.x * blockDim.x + threadIdx.x;   // s*(40*32) + head*32 + f
    int f = idx & 31;
    int head = (idx >> 5) % (NH + NKV);
    int s = idx / ((NH + NKV) * 32);
    if (s >= S_LEN) return;
    float c  = cosT[(s << 5) + f];
    float sn = sinT[(s << 5) + f];
    float* p;
    if (head < NH) p = Q + (size_t)s * HID + head * HD;
    else           p = Kb + (size_t)s * KVD + (head - NH) * HD;
    float x1 = p[f], x2 = p[f + 32];
    p[f]      = x1 * c - x2 * sn;
    p[f + 32] = x2 * c + x1 * sn;
}

// ---------------- sliding-window flash attention ----------------
// grid: (S/128, NH). block = 128 (2 waves). Wave w owns q rows [qb + w*64, +64);
// lane owns one q row. K/V tiles (64 keys x 64 dims) staged in LDS.
__global__ __launch_bounds__(128) void attn_kernel(const float* __restrict__ Q,
                                                   const float* __restrict__ K,
                                                   const float* __restrict__ V,
                                                   float* __restrict__ O) {
    __shared__ float Ks[64][64];
    __shared__ float Vs[64][64];

    const int h    = blockIdx.y;
    const int kvh  = h / GQA;
    const int qb   = blockIdx.x * 128;
    const int wave = threadIdx.x >> 6;
    const int lane = threadIdx.x & 63;
    const int row  = qb + wave * 64 + lane;

    // load this lane's q row into registers
    float qr[64];
    const float* qp = &Q[(size_t)row * HID + h * HD];
#pragma unroll
    for (int i = 0; i < 16; i++) {
        float4 v4 = *reinterpret_cast<const float4*>(qp + 4 * i);
        qr[4 * i + 0] = v4.x; qr[4 * i + 1] = v4.y;
        qr[4 * i + 2] = v4.z; qr[4 * i + 3] = v4.w;
    }

    float acc[64];
#pragma unroll
    for (int d = 0; d < 64; d++) acc[d] = 0.f;
    float mrun = -1e30f;
    float srun = 0.f;

    const int lo  = qb - (WINDOW - 1);
    const int kt0 = (lo > 0 ? lo : 0) >> 6;
    const int kt1 = (qb + 127) >> 6;

    for (int kt = kt0; kt <= kt1; kt++) {
        const int k0 = kt << 6;
        // cooperative stage of K/V tile (64 rows x 64 floats each)
#pragma unroll
        for (int i = 0; i < 8; i++) {
            int r  = (threadIdx.x >> 4) + i * 8;
            int c4 = (threadIdx.x & 15) * 4;
            size_t gidx = (size_t)(k0 + r) * KVD + kvh * HD + c4;
            *reinterpret_cast<float4*>(&Ks[r][c4]) = *reinterpret_cast<const float4*>(&K[gidx]);
            *reinterpret_cast<float4*>(&Vs[r][c4]) = *reinterpret_cast<const float4*>(&V[gidx]);
        }
        __syncthreads();

        for (int c = 0; c < 64; c++) {
            const int key = k0 + c;
            if (key > row || key < row - (WINDOW - 1)) continue;
            float d0 = 0.f, d1 = 0.f, d2 = 0.f, d3 = 0.f;
#pragma unroll
            for (int d = 0; d < 64; d += 4) {
                d0 += qr[d + 0] * Ks[c][d + 0];
                d1 += qr[d + 1] * Ks[c][d + 1];
                d2 += qr[d + 2] * Ks[c][d + 2];
                d3 += qr[d + 3] * Ks[c][d + 3];
            }
            float sdot = 0.125f * ((d0 + d1) + (d2 + d3));
            if (sdot > mrun) {
                float f = __expf(mrun - sdot);
                srun *= f;
#pragma unroll
                for (int d = 0; d < 64; d++) acc[d] *= f;
                mrun = sdot;
            }
            float p = __expf(sdot - mrun);
            srun += p;
#pragma unroll
            for (int d = 0; d < 64; d++) acc[d] += p * Vs[c][d];
        }
        __syncthreads();
    }

    const float inv = 1.0f / srun;
    float* op = &O[(size_t)row * HID + h * HD];
#pragma unroll
    for (int i = 0; i < 16; i++) {
        float4 o4 = make_float4(acc[4 * i + 0] * inv, acc[4 * i + 1] * inv,
                                acc[4 * i + 2] * inv, acc[4 * i + 3] * inv);
        *reinterpret_cast<float4*>(op + 4 * i) = o4;
    }
}

extern "C" void kernel_launch(void* const* d_in, const int* in_sizes, int n_in,
                              void* d_out, int out_size, void* d_ws, size_t ws_size,
                              hipStream_t stream) {
    const float* hs = (const float*)d_in[0];
    const float* Wq = (const float*)d_in[1];
    const float* Wk = (const float*)d_in[2];
    const float* Wv = (const float*)d_in[3];
    const float* Wo = (const float*)d_in[4];
    float* out = (float*)d_out;

    float* ws   = (float*)d_ws;
    float* cosT = ws;                       // 65536
    float* sinT = cosT + S_LEN * 32;        // 65536
    float* Qb   = sinT + S_LEN * 32;        // S*HID   = 4194304
    float* Kb   = Qb + (size_t)S_LEN * HID; // S*KVD   = 1048576
    float* Vb   = Kb + (size_t)S_LEN * KVD;
    float* Ab   = Vb + (size_t)S_LEN * KVD; // S*HID

    rope_table_kernel<<<(S_LEN * 32) / 256, 256, 0, stream>>>(cosT, sinT);

    // Q/K/V projections
    gemm_f32_kernel<<<dim3(HID / 64, S_LEN / 64), 256, 0, stream>>>(hs, Wq, Qb, S_LEN, HID, HID);
    gemm_f32_kernel<<<dim3(KVD / 64, S_LEN / 64), 256, 0, stream>>>(hs, Wk, Kb, S_LEN, KVD, HID);
    gemm_f32_kernel<<<dim3(KVD / 64, S_LEN / 64), 256, 0, stream>>>(hs, Wv, Vb, S_LEN, KVD, HID);

    // RoPE on Q and K
    rope_kernel<<<(S_LEN * (NH + NKV) * 32) / 256, 256, 0, stream>>>(Qb, Kb, cosT, sinT);

    // sliding-window attention
    attn_kernel<<<dim3(S_LEN / 128, NH), 128, 0, stream>>>(Qb, Kb, Vb, Ab);

    // output projection
    gemm_f32_kernel<<<dim3(HID / 64, S_LEN / 64), 256, 0, stream>>>(Ab, Wo, out, S_LEN, HID, HID);
}

// Round 2
// 756.125 us; speedup vs baseline: 2.3619x; 2.3619x over previous
//
#include <hip/hip_runtime.h>
#include <hip/hip_bf16.h>
#include <math.h>

#define S_LEN 2048
#define HID 2048
#define NH 32
#define NKV 8
#define HD 64
#define WINDOW 1024

typedef __attribute__((ext_vector_type(8))) short bx8;          // 8 bf16 (4 VGPRs) — MFMA A/B frag
typedef __attribute__((ext_vector_type(4))) float fx4;          // MFMA C/D frag
typedef __attribute__((ext_vector_type(8))) unsigned short us8; // 8 bf16 raw load

__device__ __forceinline__ float bf2f(unsigned short u) {
    return __uint_as_float(((unsigned)u) << 16);
}

// ---------------- RoPE tables (f64 on device, tiny) ----------------
__global__ void rope_table_kernel(float* __restrict__ cosT, float* __restrict__ sinT) {
    int idx = blockIdx.x * blockDim.x + threadIdx.x;  // s*32 + f
    if (idx >= S_LEN * 32) return;
    int s = idx >> 5, f = idx & 31;
    double inv = exp(-2.0 * (double)f / 64.0 * log(500000.0));
    double ang = (double)s * inv;
    cosT[idx] = (float)cos(ang);
    sinT[idx] = (float)sin(ang);
}

// ---------------- f32 -> bf16 elementwise (8 elems/thread) ----------------
__global__ void conv_kernel(const float* __restrict__ in, __hip_bfloat16* __restrict__ out) {
    int i = (blockIdx.x * 256 + threadIdx.x) * 8;
    float4 a = *reinterpret_cast<const float4*>(&in[i]);
    float4 b = *reinterpret_cast<const float4*>(&in[i + 4]);
    __hip_bfloat16 o[8] __attribute__((aligned(16)));
    o[0] = __float2bfloat16(a.x); o[1] = __float2bfloat16(a.y);
    o[2] = __float2bfloat16(a.z); o[3] = __float2bfloat16(a.w);
    o[4] = __float2bfloat16(b.x); o[5] = __float2bfloat16(b.y);
    o[6] = __float2bfloat16(b.z); o[7] = __float2bfloat16(b.w);
    *reinterpret_cast<bx8*>(&out[i]) = *reinterpret_cast<bx8*>(o);
}

// ---------------- transpose+convert: out[n][k](bf16) = in[k][n](f32) ----------------
__global__ void convT_kernel(const float* __restrict__ in, __hip_bfloat16* __restrict__ out,
                             int K, int N, int outStride) {
    __shared__ float tile[32][33];
    int n0 = blockIdx.x * 32, k0 = blockIdx.y * 32;
    int tx = threadIdx.x, ty = threadIdx.y;  // 32 x 8
#pragma unroll
    for (int i = 0; i < 4; i++)
        tile[ty + 8 * i][tx] = in[(size_t)(k0 + ty + 8 * i) * N + n0 + tx];
    __syncthreads();
#pragma unroll
    for (int i = 0; i < 4; i++)
        out[(size_t)(n0 + ty + 8 * i) * outStride + k0 + tx] = __float2bfloat16(tile[tx][ty + 8 * i]);
}

// ---------------- bf16 MFMA GEMM: C[M][N] = A[M][K] @ Bt[N][K]^T ----------------
// 128x128 tile, 256 thr (4 waves), each wave 64x64 = 4x4 fragments of 16x16x32.
template <int OUTBF16>
__global__ __launch_bounds__(256) void gemm_bf16_kernel(const __hip_bfloat16* __restrict__ A,
                                                        const __hip_bfloat16* __restrict__ Bt,
                                                        void* __restrict__ Cp,
                                                        int M, int N, int K) {
    __shared__ __hip_bfloat16 As[128 * 32];
    __shared__ __hip_bfloat16 Bs[128 * 32];
    const int t = threadIdx.x, w = t >> 6, l = t & 63;
    const int bm = blockIdx.y * 128, bn = blockIdx.x * 128;
    const int wr = (w >> 1) * 64, wc = (w & 1) * 64;

    fx4 acc[4][4];
#pragma unroll
    for (int m = 0; m < 4; m++)
#pragma unroll
        for (int n = 0; n < 4; n++) acc[m][n] = (fx4){0.f, 0.f, 0.f, 0.f};

    const int srow = t >> 2, skc = (t & 3) * 8;
    const int lr = l & 15, lk = (l >> 4) * 8;

    for (int k0 = 0; k0 < K; k0 += 32) {
#pragma unroll
        for (int i = 0; i < 2; i++) {
            int r = i * 64 + srow;
            *reinterpret_cast<bx8*>(&As[r * 32 + skc]) =
                *reinterpret_cast<const bx8*>(&A[(size_t)(bm + r) * K + k0 + skc]);
            *reinterpret_cast<bx8*>(&Bs[r * 32 + skc]) =
                *reinterpret_cast<const bx8*>(&Bt[(size_t)(bn + r) * K + k0 + skc]);
        }
        __syncthreads();
        bx8 af[4], bf[4];
#pragma unroll
        for (int m = 0; m < 4; m++)
            af[m] = *reinterpret_cast<const bx8*>(&As[(wr + m * 16 + lr) * 32 + lk]);
#pragma unroll
        for (int n = 0; n < 4; n++)
            bf[n] = *reinterpret_cast<const bx8*>(&Bs[(wc + n * 16 + lr) * 32 + lk]);
#pragma unroll
        for (int m = 0; m < 4; m++)
#pragma unroll
            for (int n = 0; n < 4; n++)
                acc[m][n] = __builtin_amdgcn_mfma_f32_16x16x32_bf16(af[m], bf[n], acc[m][n], 0, 0, 0);
        __syncthreads();
    }

    const int lq = (l >> 4) * 4;
#pragma unroll
    for (int m = 0; m < 4; m++)
#pragma unroll
        for (int n = 0; n < 4; n++)
#pragma unroll
            for (int r = 0; r < 4; r++) {
                int row = bm + wr + m * 16 + lq + r;
                int col = bn + wc + n * 16 + lr;
                float v = acc[m][n][r];
                if (OUTBF16)
                    ((__hip_bfloat16*)Cp)[(size_t)row * N + col] = __float2bfloat16(v);
                else
                    ((float*)Cp)[(size_t)row * N + col] = v;
            }
}

// ---------------- RoPE in-place on bf16 Q [S][2048] and K-part of KV [S][1024] ----------------
__global__ void rope_kernel(__hip_bfloat16* __restrict__ Q, __hip_bfloat16* __restrict__ KV,
                            const float* __restrict__ cosT, const float* __restrict__ sinT) {
    int idx = blockIdx.x * blockDim.x + threadIdx.x;  // s*(40*32) + head*32 + f
    int f = idx & 31;
    int head = (idx >> 5) % (NH + NKV);
    int s = idx / ((NH + NKV) * 32);
    if (s >= S_LEN) return;
    float c  = cosT[(s << 5) + f];
    float sn = sinT[(s << 5) + f];
    __hip_bfloat16* p = (head < NH) ? (Q + (size_t)s * HID + head * HD)
                                    : (KV + (size_t)s * 1024 + (head - NH) * HD);
    float x1 = __bfloat162float(p[f]), x2 = __bfloat162float(p[f + 32]);
    p[f]      = __float2bfloat16(x1 * c - x2 * sn);
    p[f + 32] = __float2bfloat16(x2 * c + x1 * sn);
}

// ---------------- sliding-window flash attention, split-K across 4 waves ----------------
// grid (S/64, NH), block 256 (4 waves). Block owns 64 q rows (1/lane); each of the
// 4 waves processes keys [w*16, w*16+16) of every 64-key tile; merge via LDS at end.
__global__ __launch_bounds__(256, 2) void attn_kernel(const __hip_bfloat16* __restrict__ Q,
                                                      const __hip_bfloat16* __restrict__ KV,
                                                      __hip_bfloat16* __restrict__ O) {
    __shared__ float smem[12672];  // stage: Ks[0..4095], Vs[4096..8191]; merge: 3x64x66
    float* Ks = smem;
    float* Vs = smem + 4096;

    const int h = blockIdx.y, kvh = h >> 2;
    const int qb = blockIdx.x * 64;
    const int t = threadIdx.x, w = t >> 6, l = t & 63;
    const int row = qb + l;
    const int w16 = w * 16;

    // q row -> f32 regs
    float qr[64];
    {
        const us8* qp = reinterpret_cast<const us8*>(Q + (size_t)row * HID + h * HD);
#pragma unroll
        for (int i = 0; i < 8; i++) {
            us8 u = qp[i];
#pragma unroll
            for (int j = 0; j < 8; j++) qr[i * 8 + j] = bf2f(u[j]);
        }
    }

    float acc[64];
#pragma unroll
    for (int d = 0; d < 64; d++) acc[d] = 0.f;
    float mrun = -1e30f, srun = 0.f;

    const int lo  = qb - (WINDOW - 1);
    const int kt0 = (lo > 0 ? lo : 0) >> 6;
    const int kt1 = (qb + 63) >> 6;

    for (int kt = kt0; kt <= kt1; kt++) {
        const int k0 = kt << 6;
        // cooperative stage of K/V tile (bf16 -> f32 LDS)
        {
            const int sr = t >> 2, sc = (t & 3) * 16;
            const us8* kp = reinterpret_cast<const us8*>(KV + (size_t)(k0 + sr) * 1024 + kvh * HD + sc);
            const us8* vp = reinterpret_cast<const us8*>(KV + (size_t)(k0 + sr) * 1024 + 512 + kvh * HD + sc);
            us8 ka = kp[0], kb = kp[1], va = vp[0], vb = vp[1];
            float* kd = &Ks[sr * 64 + sc];
            float* vd = &Vs[sr * 64 + sc];
#pragma unroll
            for (int i = 0; i < 8; i++) {
                kd[i] = bf2f(ka[i]); kd[8 + i] = bf2f(kb[i]);
                vd[i] = bf2f(va[i]); vd[8 + i] = bf2f(vb[i]);
            }
        }
        __syncthreads();

        const bool wave_active = (k0 + w16 <= qb + 63) && (k0 + w16 + 15 >= qb - (WINDOW - 1));
        if (wave_active) {
            float dots[16];
            float tmax = -1e30f;
#pragma unroll
            for (int j = 0; j < 16; j++) {
                const int key = k0 + w16 + j;
                const fx4* kr4 = reinterpret_cast<const fx4*>(&Ks[(w16 + j) * 64]);
                float d0 = 0.f, d1 = 0.f, d2 = 0.f, d3 = 0.f;
#pragma unroll
                for (int q4 = 0; q4 < 16; q4++) {
                    fx4 kk = kr4[q4];
                    d0 += qr[q4 * 4 + 0] * kk[0];
                    d1 += qr[q4 * 4 + 1] * kk[1];
                    d2 += qr[q4 * 4 + 2] * kk[2];
                    d3 += qr[q4 * 4 + 3] * kk[3];
                }
                float s = 0.125f * ((d0 + d1) + (d2 + d3));
                dots[j] = s;
                bool valid = (key <= row) && (key >= row - (WINDOW - 1));
                if (valid && s > tmax) tmax = s;
            }
            if (tmax > mrun) {
                float f = __expf(mrun - tmax);
                srun *= f;
#pragma unroll
                for (int d = 0; d < 64; d++) acc[d] *= f;
                mrun = tmax;
            }
#pragma unroll
            for (int j = 0; j < 16; j++) {
                const int key = k0 + w16 + j;
                bool valid = (key <= row) && (key >= row - (WINDOW - 1));
                float p = valid ? __expf(dots[j] - mrun) : 0.f;
                srun += p;
                const fx4* vr4 = reinterpret_cast<const fx4*>(&Vs[(w16 + j) * 64]);
#pragma unroll
                for (int q4 = 0; q4 < 16; q4++) {
                    fx4 vv = vr4[q4];
                    acc[q4 * 4 + 0] += p * vv[0];
                    acc[q4 * 4 + 1] += p * vv[1];
                    acc[q4 * 4 + 2] += p * vv[2];
                    acc[q4 * 4 + 3] += p * vv[3];
                }
            }
        }
        __syncthreads();
    }

    // merge the 4 per-wave partial softmax states
    if (w > 0) {
        float* c = smem + (size_t)(w - 1) * 4224 + l * 66;
#pragma unroll
        for (int d = 0; d < 64; d++) c[d] = acc[d];
        c[64] = mrun; c[65] = srun;
    }
    __syncthreads();
    if (w == 0) {
        for (int ww = 0; ww < 3; ww++) {
            const float* c = smem + (size_t)ww * 4224 + l * 66;
            float mw = c[64], sw = c[65];
            float M  = fmaxf(mrun, mw);
            float f0 = __expf(mrun - M), f1 = __expf(mw - M);
            srun = srun * f0 + sw * f1;
#pragma unroll
            for (int d = 0; d < 64; d++) acc[d] = acc[d] * f0 + c[d] * f1;
            mrun = M;
        }
        float inv = 1.0f / srun;
        float* fin = smem + l * 66;
#pragma unroll
        for (int d = 0; d < 64; d++) fin[d] = acc[d] * inv;
    }
    __syncthreads();
    // cooperative bf16 store of the 64x64 output block
    {
        const int sr = t >> 2, sc = (t & 3) * 16;
        const float* fin = smem + sr * 66 + sc;
        __hip_bfloat16 ob[16] __attribute__((aligned(16)));
#pragma unroll
        for (int i = 0; i < 16; i++) ob[i] = __float2bfloat16(fin[i]);
        __hip_bfloat16* op = O + (size_t)(qb + sr) * HID + h * HD + sc;
        *reinterpret_cast<bx8*>(op)     = *reinterpret_cast<bx8*>(&ob[0]);
        *reinterpret_cast<bx8*>(op + 8) = *reinterpret_cast<bx8*>(&ob[8]);
    }
}

extern "C" void kernel_launch(void* const* d_in, const int* in_sizes, int n_in,
                              void* d_out, int out_size, void* d_ws, size_t ws_size,
                              hipStream_t stream) {
    const float* hs = (const float*)d_in[0];
    const float* Wq = (const float*)d_in[1];
    const float* Wk = (const float*)d_in[2];
    const float* Wv = (const float*)d_in[3];
    const float* Wo = (const float*)d_in[4];

    float* ws   = (float*)d_ws;
    float* cosT = ws;                 // 65536 f32
    float* sinT = cosT + 65536;       // 65536 f32
    __hip_bfloat16* hsb  = (__hip_bfloat16*)(sinT + 65536);  // [2048][2048]
    __hip_bfloat16* WqT  = hsb + 4194304;                    // [2048][2048]
    __hip_bfloat16* WkvT = WqT + 4194304;                    // [1024][2048] (K rows 0-511, V rows 512-1023)
    __hip_bfloat16* WoT  = WkvT + 2097152;                   // [2048][2048]
    __hip_bfloat16* Qb   = WoT + 4194304;                    // [2048][2048]
    __hip_bfloat16* KVb  = Qb + 4194304;                     // [2048][1024]
    __hip_bfloat16* Ab   = hsb;                              // alias: hsb dead after KV gemm

    rope_table_kernel<<<(S_LEN * 32) / 256, 256, 0, stream>>>(cosT, sinT);
    conv_kernel<<<2048, 256, 0, stream>>>(hs, hsb);
    convT_kernel<<<dim3(64, 64), dim3(32, 8), 0, stream>>>(Wq, WqT, 2048, 2048, 2048);
    convT_kernel<<<dim3(16, 64), dim3(32, 8), 0, stream>>>(Wk, WkvT, 2048, 512, 2048);
    convT_kernel<<<dim3(16, 64), dim3(32, 8), 0, stream>>>(Wv, WkvT + (size_t)512 * 2048, 2048, 512, 2048);
    convT_kernel<<<dim3(64, 64), dim3(32, 8), 0, stream>>>(Wo, WoT, 2048, 2048, 2048);

    gemm_bf16_kernel<1><<<dim3(16, 16), 256, 0, stream>>>(hsb, WqT, Qb, 2048, 2048, 2048);
    gemm_bf16_kernel<1><<<dim3(8, 16), 256, 0, stream>>>(hsb, WkvT, KVb, 2048, 1024, 2048);

    rope_kernel<<<(S_LEN * (NH + NKV) * 32) / 256, 256, 0, stream>>>(Qb, KVb, cosT, sinT);

    attn_kernel<<<dim3(32, 32), 256, 0, stream>>>(Qb, KVb, Ab);

    gemm_bf16_kernel<0><<<dim3(16, 16), 256, 0, stream>>>(Ab, WoT, d_out, 2048, 2048, 2048);
}

// Round 4
// 287.007 us; speedup vs baseline: 6.2225x; 2.6345x over previous
//
#include <hip/hip_runtime.h>
#include <hip/hip_bf16.h>
#include <math.h>

#define S_LEN 2048
#define HID 2048
#define NH 32
#define NKV 8
#define HD 64
#define WINDOW 1024
#define QBLK 128

typedef __attribute__((ext_vector_type(8))) short bx8;          // 8 bf16 (4 VGPRs) — MFMA A/B frag
typedef __attribute__((ext_vector_type(4))) float fx4;          // MFMA C/D frag
typedef __attribute__((ext_vector_type(8))) unsigned short us8; // 8 bf16 raw

// ---------------- RoPE tables (f64 on device, tiny) ----------------
__global__ void rope_table_kernel(float* __restrict__ cosT, float* __restrict__ sinT) {
    int idx = blockIdx.x * blockDim.x + threadIdx.x;  // s*32 + f
    if (idx >= S_LEN * 32) return;
    int s = idx >> 5, f = idx & 31;
    double inv = exp(-2.0 * (double)f / 64.0 * log(500000.0));
    double ang = (double)s * inv;
    cosT[idx] = (float)cos(ang);
    sinT[idx] = (float)sin(ang);
}

// ---------------- f32 -> bf16 elementwise ----------------
__global__ void conv_kernel(const float* __restrict__ in, __hip_bfloat16* __restrict__ out) {
    int i = (blockIdx.x * 256 + threadIdx.x) * 8;
    float4 a = *reinterpret_cast<const float4*>(&in[i]);
    float4 b = *reinterpret_cast<const float4*>(&in[i + 4]);
    __hip_bfloat16 o[8] __attribute__((aligned(16)));
    o[0] = __float2bfloat16(a.x); o[1] = __float2bfloat16(a.y);
    o[2] = __float2bfloat16(a.z); o[3] = __float2bfloat16(a.w);
    o[4] = __float2bfloat16(b.x); o[5] = __float2bfloat16(b.y);
    o[6] = __float2bfloat16(b.z); o[7] = __float2bfloat16(b.w);
    *reinterpret_cast<bx8*>(&out[i]) = *reinterpret_cast<bx8*>(o);
}

// ---------------- transpose+convert: out[n][k](bf16) = in[k][n](f32) ----------------
__global__ void convT_kernel(const float* __restrict__ in, __hip_bfloat16* __restrict__ out,
                             int K, int N, int outStride) {
    __shared__ float tile[32][33];
    int n0 = blockIdx.x * 32, k0 = blockIdx.y * 32;
    int tx = threadIdx.x, ty = threadIdx.y;  // 32 x 8
#pragma unroll
    for (int i = 0; i < 4; i++)
        tile[ty + 8 * i][tx] = in[(size_t)(k0 + ty + 8 * i) * N + n0 + tx];
    __syncthreads();
#pragma unroll
    for (int i = 0; i < 4; i++)
        out[(size_t)(n0 + ty + 8 * i) * outStride + k0 + tx] = __float2bfloat16(tile[tx][ty + 8 * i]);
}

// ---------------- bf16 MFMA GEMM: C[M][N] = A[M][K] @ Bt[N][K]^T ----------------
template <int OUTBF16>
__global__ __launch_bounds__(256) void gemm_bf16_kernel(const __hip_bfloat16* __restrict__ A,
                                                        const __hip_bfloat16* __restrict__ Bt,
                                                        void* __restrict__ Cp,
                                                        int M, int N, int K) {
    __shared__ __hip_bfloat16 As[128 * 32];
    __shared__ __hip_bfloat16 Bs[128 * 32];
    const int t = threadIdx.x, w = t >> 6, l = t & 63;
    const int bm = blockIdx.y * 128, bn = blockIdx.x * 128;
    const int wr = (w >> 1) * 64, wc = (w & 1) * 64;

    fx4 acc[4][4];
#pragma unroll
    for (int m = 0; m < 4; m++)
#pragma unroll
        for (int n = 0; n < 4; n++) acc[m][n] = (fx4){0.f, 0.f, 0.f, 0.f};

    const int srow = t >> 2, skc = (t & 3) * 8;
    const int lr = l & 15, lk = (l >> 4) * 8;

    for (int k0 = 0; k0 < K; k0 += 32) {
#pragma unroll
        for (int i = 0; i < 2; i++) {
            int r = i * 64 + srow;
            *reinterpret_cast<bx8*>(&As[r * 32 + skc]) =
                *reinterpret_cast<const bx8*>(&A[(size_t)(bm + r) * K + k0 + skc]);
            *reinterpret_cast<bx8*>(&Bs[r * 32 + skc]) =
                *reinterpret_cast<const bx8*>(&Bt[(size_t)(bn + r) * K + k0 + skc]);
        }
        __syncthreads();
        bx8 af[4], bf[4];
#pragma unroll
        for (int m = 0; m < 4; m++)
            af[m] = *reinterpret_cast<const bx8*>(&As[(wr + m * 16 + lr) * 32 + lk]);
#pragma unroll
        for (int n = 0; n < 4; n++)
            bf[n] = *reinterpret_cast<const bx8*>(&Bs[(wc + n * 16 + lr) * 32 + lk]);
#pragma unroll
        for (int m = 0; m < 4; m++)
#pragma unroll
            for (int n = 0; n < 4; n++)
                acc[m][n] = __builtin_amdgcn_mfma_f32_16x16x32_bf16(af[m], bf[n], acc[m][n], 0, 0, 0);
        __syncthreads();
    }

    const int lq = (l >> 4) * 4;
#pragma unroll
    for (int m = 0; m < 4; m++)
#pragma unroll
        for (int n = 0; n < 4; n++)
#pragma unroll
            for (int r = 0; r < 4; r++) {
                int row = bm + wr + m * 16 + lq + r;
                int col = bn + wc + n * 16 + lr;
                float v = acc[m][n][r];
                if (OUTBF16)
                    ((__hip_bfloat16*)Cp)[(size_t)row * N + col] = __float2bfloat16(v);
                else
                    ((float*)Cp)[(size_t)row * N + col] = v;
            }
}

// ---------------- RoPE in-place on bf16 Q [S][2048] and K [S][512] ----------------
__global__ void rope_kernel(__hip_bfloat16* __restrict__ Q, __hip_bfloat16* __restrict__ Kb,
                            const float* __restrict__ cosT, const float* __restrict__ sinT) {
    int idx = blockIdx.x * blockDim.x + threadIdx.x;  // s*(40*32) + head*32 + f
    int f = idx & 31;
    int head = (idx >> 5) % (NH + NKV);
    int s = idx / ((NH + NKV) * 32);
    if (s >= S_LEN) return;
    float c  = cosT[(s << 5) + f];
    float sn = sinT[(s << 5) + f];
    __hip_bfloat16* p = (head < NH) ? (Q + (size_t)s * HID + head * HD)
                                    : (Kb + (size_t)s * 512 + (head - NH) * HD);
    float x1 = __bfloat162float(p[f]), x2 = __bfloat162float(p[f + 32]);
    p[f]      = __float2bfloat16(x1 * c - x2 * sn);
    p[f + 32] = __float2bfloat16(x2 * c + x1 * sn);
}

// ---------------- MFMA sliding-window flash attention ----------------
// 1D grid of 512 blocks (XCD-swizzled -> (head, q-tile)). 256 thr = 4 waves.
// Wave w owns q rows [qb+32w, qb+32w+32) as 2 m-frags of 16x16x32 MFMA.
// K tile [64 key][64 d], Vt tile [64 d][64 key], P [128 q][64 key] in LDS (XOR swz).
__global__ __launch_bounds__(256) void attn_kernel(const __hip_bfloat16* __restrict__ Q,
                                                   const __hip_bfloat16* __restrict__ Kg,
                                                   const __hip_bfloat16* __restrict__ Vtg,
                                                   __hip_bfloat16* __restrict__ O) {
    __shared__ __hip_bfloat16 Ks[64 * 64];
    __shared__ __hip_bfloat16 Vs[64 * 64];
    __shared__ __hip_bfloat16 Ps[QBLK * 64];

    // XCD swizzle: 512 blocks, 8 XCDs -> each XCD gets 4 consecutive heads' blocks
    const int bid = blockIdx.x;
    const int swz = (bid & 7) * 64 + (bid >> 3);
    const int h = swz >> 4, qi = swz & 15;
    const int qb = qi * QBLK;
    const int kvh = h >> 2;

    const int t = threadIdx.x, w = t >> 6, l = t & 63;
    const int lr = l & 15, g = l >> 4, lk = g * 8;
    const int qbw = qb + 32 * w;

    char* KsB = (char*)Ks;
    char* VsB = (char*)Vs;
    char* PsB = (char*)Ps;

    // hoisted Q fragments
    bx8 qa[2][2];
#pragma unroll
    for (int mf = 0; mf < 2; mf++)
#pragma unroll
        for (int ks = 0; ks < 2; ks++)
            qa[mf][ks] = *reinterpret_cast<const bx8*>(
                &Q[(size_t)(qbw + 16 * mf + lr) * HID + h * HD + ks * 32 + lk]);

    fx4 o[2][4];
    float mrow[2][4], srow[2][4];
#pragma unroll
    for (int mf = 0; mf < 2; mf++)
#pragma unroll
        for (int n = 0; n < 4; n++) o[mf][n] = (fx4){0.f, 0.f, 0.f, 0.f};
#pragma unroll
    for (int mf = 0; mf < 2; mf++)
#pragma unroll
        for (int r = 0; r < 4; r++) { mrow[mf][r] = -1e30f; srow[mf][r] = 0.f; }

    // first tile containing any valid key: floor((qb-1023)/64)*64 = qb-1024 (qb>=1024)
    const int k0_first = (qb >= 1024) ? (qb - 1024) : 0;
    const int k0_last  = qb + 64;
    const int wmax = qbw + 31;

    for (int k0 = k0_first; k0 <= k0_last; k0 += 64) {
        // ---- stage K and Vt tiles (bf16, XOR-swizzled) ----
#pragma unroll
        for (int j = 0; j < 2; j++) {
            int idx = t + 256 * j;           // 0..511
            int row = idx >> 3;              // 0..63
            int cb  = (idx & 7) * 16;        // byte col
            int dst = row * 128 + (cb ^ ((row & 7) << 4));
            us8 kv = *reinterpret_cast<const us8*>(&Kg[(size_t)(k0 + row) * 512 + kvh * HD + (idx & 7) * 8]);
            *reinterpret_cast<us8*>(KsB + dst) = kv;
            us8 vv = *reinterpret_cast<const us8*>(&Vtg[(size_t)(kvh * HD + row) * S_LEN + k0 + (idx & 7) * 8]);
            *reinterpret_cast<us8*>(VsB + dst) = vv;
        }
        __syncthreads();

        if (k0 <= wmax) {
            // ---- K fragments ----
            bx8 kb[4][2];
#pragma unroll
            for (int n = 0; n < 4; n++)
#pragma unroll
                for (int ks = 0; ks < 2; ks++) {
                    int row = 16 * n + lr;
                    kb[n][ks] = *reinterpret_cast<const bx8*>(
                        KsB + row * 128 + (((ks * 64) + 16 * g) ^ ((row & 7) << 4)));
                }
            // ---- QK^T + softmax + P-write, per m-frag ----
#pragma unroll
            for (int mf = 0; mf < 2; mf++) {
                fx4 sc[4];
#pragma unroll
                for (int n = 0; n < 4; n++) {
                    sc[n] = __builtin_amdgcn_mfma_f32_16x16x32_bf16(qa[mf][0], kb[n][0],
                                                                    (fx4){0.f, 0.f, 0.f, 0.f}, 0, 0, 0);
                    sc[n] = __builtin_amdgcn_mfma_f32_16x16x32_bf16(qa[mf][1], kb[n][1], sc[n], 0, 0, 0);
                }
                // sliding-window mask (both edges) + scale
#pragma unroll
                for (int n = 0; n < 4; n++) {
                    int col = k0 + 16 * n + lr;
#pragma unroll
                    for (int r = 0; r < 4; r++) {
                        int rowq = qbw + 16 * mf + 4 * g + r;
                        bool valid = (col <= rowq) && (col >= rowq - (WINDOW - 1));
                        sc[n][r] = valid ? sc[n][r] * 0.125f : -1e30f;
                    }
                }
#pragma unroll
                for (int r = 0; r < 4; r++) {
                    float tmax = fmaxf(fmaxf(sc[0][r], sc[1][r]), fmaxf(sc[2][r], sc[3][r]));
                    tmax = fmaxf(tmax, __shfl_xor(tmax, 1));
                    tmax = fmaxf(tmax, __shfl_xor(tmax, 2));
                    tmax = fmaxf(tmax, __shfl_xor(tmax, 4));
                    tmax = fmaxf(tmax, __shfl_xor(tmax, 8));
                    float mo = mrow[mf][r];
                    float mn = fmaxf(mo, tmax);
                    float fs = __expf(mo - mn);
                    mrow[mf][r] = mn;
                    float ps = 0.f;
#pragma unroll
                    for (int n = 0; n < 4; n++) {
                        float p = __expf(sc[n][r] - mn);
                        sc[n][r] = p;
                        ps += p;
                    }
                    ps += __shfl_xor(ps, 1);
                    ps += __shfl_xor(ps, 2);
                    ps += __shfl_xor(ps, 4);
                    ps += __shfl_xor(ps, 8);
                    srow[mf][r] = srow[mf][r] * fs + ps;
#pragma unroll
                    for (int n = 0; n < 4; n++) o[mf][n][r] *= fs;
                }
                // write P tile rows (wave-private, no block barrier needed)
#pragma unroll
                for (int r = 0; r < 4; r++) {
                    int prow = 32 * w + 16 * mf + 4 * g + r;
                    char* pb = PsB + prow * 128;
                    int sz = (prow & 7) << 4;
#pragma unroll
                    for (int n = 0; n < 4; n++)
                        *reinterpret_cast<__hip_bfloat16*>(pb + (((16 * n + lr) * 2) ^ sz)) =
                            __float2bfloat16(sc[n][r]);
                }
            }
            // ---- V fragments + PV ----
            bx8 vb[4][2];
#pragma unroll
            for (int n = 0; n < 4; n++)
#pragma unroll
                for (int ks = 0; ks < 2; ks++) {
                    int row = 16 * n + lr;
                    vb[n][ks] = *reinterpret_cast<const bx8*>(
                        VsB + row * 128 + (((ks * 64) + 16 * g) ^ ((row & 7) << 4)));
                }
#pragma unroll
            for (int mf = 0; mf < 2; mf++) {
                bx8 pa[2];
#pragma unroll
                for (int ks = 0; ks < 2; ks++) {
                    int prow = 32 * w + 16 * mf + lr;
                    pa[ks] = *reinterpret_cast<const bx8*>(
                        PsB + prow * 128 + (((ks * 64) + 16 * g) ^ ((prow & 7) << 4)));
                }
#pragma unroll
                for (int n = 0; n < 4; n++) {
                    o[mf][n] = __builtin_amdgcn_mfma_f32_16x16x32_bf16(pa[0], vb[n][0], o[mf][n], 0, 0, 0);
                    o[mf][n] = __builtin_amdgcn_mfma_f32_16x16x32_bf16(pa[1], vb[n][1], o[mf][n], 0, 0, 0);
                }
            }
        }
        __syncthreads();
    }

    // ---- epilogue: normalize + store ----
#pragma unroll
    for (int mf = 0; mf < 2; mf++) {
        float inv[4];
#pragma unroll
        for (int r = 0; r < 4; r++) inv[r] = 1.f / srow[mf][r];
#pragma unroll
        for (int n = 0; n < 4; n++)
#pragma unroll
            for (int r = 0; r < 4; r++) {
                int rq = qbw + 16 * mf + 4 * g + r;
                O[(size_t)rq * HID + h * HD + 16 * n + lr] = __float2bfloat16(o[mf][n][r] * inv[r]);
            }
    }
}

extern "C" void kernel_launch(void* const* d_in, const int* in_sizes, int n_in,
                              void* d_out, int out_size, void* d_ws, size_t ws_size,
                              hipStream_t stream) {
    const float* hs = (const float*)d_in[0];
    const float* Wq = (const float*)d_in[1];
    const float* Wk = (const float*)d_in[2];
    const float* Wv = (const float*)d_in[3];
    const float* Wo = (const float*)d_in[4];

    float* ws   = (float*)d_ws;
    float* cosT = ws;                 // 65536 f32
    float* sinT = cosT + 65536;       // 65536 f32
    __hip_bfloat16* hsb = (__hip_bfloat16*)(sinT + 65536);   // [2048][2048]
    __hip_bfloat16* WqT = hsb + 4194304;                     // [2048][2048]
    __hip_bfloat16* WkT = WqT + 4194304;                     // [512][2048]
    __hip_bfloat16* WvT = WkT + 1048576;                     // [512][2048]
    __hip_bfloat16* WoT = WvT + 1048576;                     // [2048][2048]
    __hip_bfloat16* Qb  = WoT + 4194304;                     // [2048][2048]
    __hip_bfloat16* Kb  = Qb + 4194304;                      // [2048][512]
    __hip_bfloat16* Vt  = Kb + 1048576;                      // [512][2048]
    __hip_bfloat16* Ab  = hsb;                               // alias: hsb dead after V^T gemm

    rope_table_kernel<<<(S_LEN * 32) / 256, 256, 0, stream>>>(cosT, sinT);
    conv_kernel<<<2048, 256, 0, stream>>>(hs, hsb);
    convT_kernel<<<dim3(64, 64), dim3(32, 8), 0, stream>>>(Wq, WqT, 2048, 2048, 2048);
    convT_kernel<<<dim3(16, 64), dim3(32, 8), 0, stream>>>(Wk, WkT, 2048, 512, 2048);
    convT_kernel<<<dim3(16, 64), dim3(32, 8), 0, stream>>>(Wv, WvT, 2048, 512, 2048);
    convT_kernel<<<dim3(64, 64), dim3(32, 8), 0, stream>>>(Wo, WoT, 2048, 2048, 2048);

    gemm_bf16_kernel<1><<<dim3(16, 16), 256, 0, stream>>>(hsb, WqT, Qb, 2048, 2048, 2048);
    gemm_bf16_kernel<1><<<dim3(4, 16), 256, 0, stream>>>(hsb, WkT, Kb, 2048, 512, 2048);
    // V^T[512][2048] = WvT[512][2048] @ hsb[2048][2048]^T  (so PV reads are key-contiguous)
    gemm_bf16_kernel<1><<<dim3(16, 4), 256, 0, stream>>>(WvT, hsb, Vt, 512, 2048, 2048);

    rope_kernel<<<(S_LEN * (NH + NKV) * 32) / 256, 256, 0, stream>>>(Qb, Kb, cosT, sinT);

    attn_kernel<<<512, 256, 0, stream>>>(Qb, Kb, Vt, Ab);

    gemm_bf16_kernel<0><<<dim3(16, 16), 256, 0, stream>>>(Ab, WoT, d_out, 2048, 2048, 2048);
}

// Round 5
// 200.230 us; speedup vs baseline: 8.9192x; 1.4334x over previous
//
#include <hip/hip_runtime.h>
#include <hip/hip_bf16.h>
#include <math.h>

#define S_LEN 2048
#define HID 2048
#define NH 32
#define NKV 8
#define HD 64
#define WINDOW 1024
#define QBLK 128
#define QKVN 3072   // fused Q(2048) | K(512) | V(512) columns

typedef __attribute__((ext_vector_type(8))) short bx8;          // 8 bf16 (4 VGPRs) — MFMA A/B frag
typedef __attribute__((ext_vector_type(4))) float fx4;          // MFMA C/D frag
typedef __attribute__((ext_vector_type(8))) unsigned short us8; // 8 bf16 raw

#define GL_LDS16(gp, lp) \
    __builtin_amdgcn_global_load_lds((__attribute__((address_space(1))) const void*)(gp), \
                                     (__attribute__((address_space(3))) void*)(lp), 16, 0, 0)

// ---------------- RoPE tables (f64 on device, tiny) ----------------
__global__ void rope_table_kernel(float* __restrict__ cosT, float* __restrict__ sinT) {
    int idx = blockIdx.x * blockDim.x + threadIdx.x;  // s*32 + f
    if (idx >= S_LEN * 32) return;
    int s = idx >> 5, f = idx & 31;
    double inv = exp(-2.0 * (double)f / 64.0 * log(500000.0));
    double ang = (double)s * inv;
    cosT[idx] = (float)cos(ang);
    sinT[idx] = (float)sin(ang);
}

// ---------------- f32 -> bf16 elementwise ----------------
__global__ void conv_kernel(const float* __restrict__ in, __hip_bfloat16* __restrict__ out) {
    int i = (blockIdx.x * 256 + threadIdx.x) * 8;
    float4 a = *reinterpret_cast<const float4*>(&in[i]);
    float4 b = *reinterpret_cast<const float4*>(&in[i + 4]);
    __hip_bfloat16 o[8] __attribute__((aligned(16)));
    o[0] = __float2bfloat16(a.x); o[1] = __float2bfloat16(a.y);
    o[2] = __float2bfloat16(a.z); o[3] = __float2bfloat16(a.w);
    o[4] = __float2bfloat16(b.x); o[5] = __float2bfloat16(b.y);
    o[6] = __float2bfloat16(b.z); o[7] = __float2bfloat16(b.w);
    *reinterpret_cast<bx8*>(&out[i]) = *reinterpret_cast<bx8*>(o);
}

// ---------------- transpose+convert: out[n][k](bf16) = in[k][n](f32) ----------------
__global__ void convT_kernel(const float* __restrict__ in, __hip_bfloat16* __restrict__ out,
                             int K, int N, int outStride) {
    __shared__ float tile[32][33];
    int n0 = blockIdx.x * 32, k0 = blockIdx.y * 32;
    int tx = threadIdx.x, ty = threadIdx.y;  // 32 x 8
#pragma unroll
    for (int i = 0; i < 4; i++)
        tile[ty + 8 * i][tx] = in[(size_t)(k0 + ty + 8 * i) * N + n0 + tx];
    __syncthreads();
#pragma unroll
    for (int i = 0; i < 4; i++)
        out[(size_t)(n0 + ty + 8 * i) * outStride + k0 + tx] = __float2bfloat16(tile[tx][ty + 8 * i]);
}

// ---------------- bf16 transpose: Vt[d][s] = QKV[s][2560+d] ----------------
__global__ void vtrans_kernel(const __hip_bfloat16* __restrict__ QKV, __hip_bfloat16* __restrict__ Vt) {
    __shared__ __hip_bfloat16 tile[32][33];
    int s0 = blockIdx.x * 32, d0 = blockIdx.y * 32;
    int tx = threadIdx.x, ty = threadIdx.y;  // 32 x 8
#pragma unroll
    for (int i = 0; i < 4; i++)
        tile[ty + 8 * i][tx] = QKV[(size_t)(s0 + ty + 8 * i) * QKVN + 2560 + d0 + tx];
    __syncthreads();
#pragma unroll
    for (int i = 0; i < 4; i++)
        Vt[(size_t)(d0 + ty + 8 * i) * S_LEN + s0 + tx] = tile[tx][ty + 8 * i];
}

// ---------------- pipelined bf16 MFMA GEMM: C[M][N] = A[M][K] @ Bt[N][K]^T ----------------
// 128x128 tile, 4 waves. global_load_lds (16B) staging, 3 LDS buffers, prefetch
// depth 2, counted vmcnt(4) (T3+T4 recipe), raw s_barrier so loads stay in flight.
template <int OUTBF16>
__global__ __launch_bounds__(256) void gemm_pipe_kernel(const __hip_bfloat16* __restrict__ A,
                                                        const __hip_bfloat16* __restrict__ Bt,
                                                        void* __restrict__ Cp,
                                                        int M, int N, int K, int nbx) {
    __shared__ __hip_bfloat16 As[3][4096];   // 3 x [128 rows][32 k] bf16
    __shared__ __hip_bfloat16 Bs[3][4096];

    // XCD-aware swizzle (gridDim.x % 8 == 0 for all launches here)
    const int nwg = gridDim.x, cpx = nwg >> 3, bid = blockIdx.x;
    const int swz = (bid & 7) * cpx + (bid >> 3);
    const int bm = (swz / nbx) * 128, bn = (swz % nbx) * 128;

    const int t = threadIdx.x, w = t >> 6, l = t & 63;
    const int wr = (w >> 1) * 64, wc = (w & 1) * 64;
    const int lr = l & 15, lk = (l >> 4) * 8;
    const int srow = w * 16 + (l >> 2);      // staging row (first half)
    const int scol = (l & 3) * 8;            // staging col (bf16)
    const int ldsoff = w * 512;              // wave-uniform LDS base (bf16 elems): w*16 rows * 32

    const __hip_bfloat16* ga0 = A + (size_t)(bm + srow) * K + scol;
    const __hip_bfloat16* gb0 = Bt + (size_t)(bn + srow) * K + scol;
    const size_t half = (size_t)64 * K;

    fx4 acc[4][4];
#pragma unroll
    for (int m = 0; m < 4; m++)
#pragma unroll
        for (int n = 0; n < 4; n++) acc[m][n] = (fx4){0.f, 0.f, 0.f, 0.f};

    const int T = K >> 5;

#define STAGE(kt, b)                                              \
    do {                                                          \
        const __hip_bfloat16* ga = ga0 + (kt) * 32;               \
        const __hip_bfloat16* gb = gb0 + (kt) * 32;               \
        GL_LDS16(ga,        &As[(b)][ldsoff]);                    \
        GL_LDS16(ga + half, &As[(b)][2048 + ldsoff]);             \
        GL_LDS16(gb,        &Bs[(b)][ldsoff]);                    \
        GL_LDS16(gb + half, &Bs[(b)][2048 + ldsoff]);             \
    } while (0)

    STAGE(0, 0);
    STAGE(1, 1);

    for (int i = 0; i < T; i++) {
        const int r = i % 3;
        if (i + 1 < T) asm volatile("s_waitcnt vmcnt(4)" ::: "memory");
        else           asm volatile("s_waitcnt vmcnt(0)" ::: "memory");
        __builtin_amdgcn_s_barrier();
        asm volatile("" ::: "memory");   // pin LDS ops after the barrier
        if (i + 2 < T) STAGE(i + 2, (i + 2) % 3);

        bx8 af[4], bf[4];
#pragma unroll
        for (int m = 0; m < 4; m++)
            af[m] = *reinterpret_cast<const bx8*>(&As[r][(wr + m * 16 + lr) * 32 + lk]);
#pragma unroll
        for (int n = 0; n < 4; n++)
            bf[n] = *reinterpret_cast<const bx8*>(&Bs[r][(wc + n * 16 + lr) * 32 + lk]);
#pragma unroll
        for (int m = 0; m < 4; m++)
#pragma unroll
            for (int n = 0; n < 4; n++)
                acc[m][n] = __builtin_amdgcn_mfma_f32_16x16x32_bf16(af[m], bf[n], acc[m][n], 0, 0, 0);
    }
#undef STAGE

    const int lq = (l >> 4) * 4;
#pragma unroll
    for (int m = 0; m < 4; m++)
#pragma unroll
        for (int n = 0; n < 4; n++)
#pragma unroll
            for (int r2 = 0; r2 < 4; r2++) {
                int row = bm + wr + m * 16 + lq + r2;
                int col = bn + wc + n * 16 + lr;
                float v = acc[m][n][r2];
                if (OUTBF16)
                    ((__hip_bfloat16*)Cp)[(size_t)row * N + col] = __float2bfloat16(v);
                else
                    ((float*)Cp)[(size_t)row * N + col] = v;
            }
}

// ---------------- RoPE in-place on fused QKV [S][3072] (Q cols 0-2047, K cols 2048-2559) ----------------
__global__ void rope_kernel(__hip_bfloat16* __restrict__ QKV,
                            const float* __restrict__ cosT, const float* __restrict__ sinT) {
    int idx = blockIdx.x * blockDim.x + threadIdx.x;  // s*(40*32) + head*32 + f
    int f = idx & 31;
    int head = (idx >> 5) % (NH + NKV);
    int s = idx / ((NH + NKV) * 32);
    if (s >= S_LEN) return;
    float c  = cosT[(s << 5) + f];
    float sn = sinT[(s << 5) + f];
    __hip_bfloat16* p = (head < NH) ? (QKV + (size_t)s * QKVN + head * HD)
                                    : (QKV + (size_t)s * QKVN + 2048 + (head - NH) * HD);
    float x1 = __bfloat162float(p[f]), x2 = __bfloat162float(p[f + 32]);
    p[f]      = __float2bfloat16(x1 * c - x2 * sn);
    p[f + 32] = __float2bfloat16(x2 * c + x1 * sn);
}

// ---------------- MFMA sliding-window flash attention (frozen from R4, strides fused) ----------------
__global__ __launch_bounds__(256) void attn_kernel(const __hip_bfloat16* __restrict__ Q,
                                                   const __hip_bfloat16* __restrict__ Kg,
                                                   const __hip_bfloat16* __restrict__ Vtg,
                                                   __hip_bfloat16* __restrict__ O) {
    __shared__ __hip_bfloat16 Ks[64 * 64];
    __shared__ __hip_bfloat16 Vs[64 * 64];
    __shared__ __hip_bfloat16 Ps[QBLK * 64];

    const int bid = blockIdx.x;
    const int swz = (bid & 7) * 64 + (bid >> 3);
    const int h = swz >> 4, qi = swz & 15;
    const int qb = qi * QBLK;
    const int kvh = h >> 2;

    const int t = threadIdx.x, w = t >> 6, l = t & 63;
    const int lr = l & 15, g = l >> 4, lk = g * 8;
    const int qbw = qb + 32 * w;

    char* KsB = (char*)Ks;
    char* VsB = (char*)Vs;
    char* PsB = (char*)Ps;

    bx8 qa[2][2];
#pragma unroll
    for (int mf = 0; mf < 2; mf++)
#pragma unroll
        for (int ks = 0; ks < 2; ks++)
            qa[mf][ks] = *reinterpret_cast<const bx8*>(
                &Q[(size_t)(qbw + 16 * mf + lr) * QKVN + h * HD + ks * 32 + lk]);

    fx4 o[2][4];
    float mrow[2][4], srow[2][4];
#pragma unroll
    for (int mf = 0; mf < 2; mf++)
#pragma unroll
        for (int n = 0; n < 4; n++) o[mf][n] = (fx4){0.f, 0.f, 0.f, 0.f};
#pragma unroll
    for (int mf = 0; mf < 2; mf++)
#pragma unroll
        for (int r = 0; r < 4; r++) { mrow[mf][r] = -1e30f; srow[mf][r] = 0.f; }

    const int k0_first = (qb >= 1024) ? (qb - 1024) : 0;
    const int k0_last  = qb + 64;
    const int wmax = qbw + 31;

    for (int k0 = k0_first; k0 <= k0_last; k0 += 64) {
#pragma unroll
        for (int j = 0; j < 2; j++) {
            int idx = t + 256 * j;
            int row = idx >> 3;
            int cb  = (idx & 7) * 16;
            int dst = row * 128 + (cb ^ ((row & 7) << 4));
            us8 kv = *reinterpret_cast<const us8*>(&Kg[(size_t)(k0 + row) * QKVN + kvh * HD + (idx & 7) * 8]);
            *reinterpret_cast<us8*>(KsB + dst) = kv;
            us8 vv = *reinterpret_cast<const us8*>(&Vtg[(size_t)(kvh * HD + row) * S_LEN + k0 + (idx & 7) * 8]);
            *reinterpret_cast<us8*>(VsB + dst) = vv;
        }
        __syncthreads();

        if (k0 <= wmax) {
            bx8 kb[4][2];
#pragma unroll
            for (int n = 0; n < 4; n++)
#pragma unroll
                for (int ks = 0; ks < 2; ks++) {
                    int row = 16 * n + lr;
                    kb[n][ks] = *reinterpret_cast<const bx8*>(
                        KsB + row * 128 + (((ks * 64) + 16 * g) ^ ((row & 7) << 4)));
                }
#pragma unroll
            for (int mf = 0; mf < 2; mf++) {
                fx4 sc[4];
#pragma unroll
                for (int n = 0; n < 4; n++) {
                    sc[n] = __builtin_amdgcn_mfma_f32_16x16x32_bf16(qa[mf][0], kb[n][0],
                                                                    (fx4){0.f, 0.f, 0.f, 0.f}, 0, 0, 0);
                    sc[n] = __builtin_amdgcn_mfma_f32_16x16x32_bf16(qa[mf][1], kb[n][1], sc[n], 0, 0, 0);
                }
#pragma unroll
                for (int n = 0; n < 4; n++) {
                    int col = k0 + 16 * n + lr;
#pragma unroll
                    for (int r = 0; r < 4; r++) {
                        int rowq = qbw + 16 * mf + 4 * g + r;
                        bool valid = (col <= rowq) && (col >= rowq - (WINDOW - 1));
                        sc[n][r] = valid ? sc[n][r] * 0.125f : -1e30f;
                    }
                }
#pragma unroll
                for (int r = 0; r < 4; r++) {
                    float tmax = fmaxf(fmaxf(sc[0][r], sc[1][r]), fmaxf(sc[2][r], sc[3][r]));
                    tmax = fmaxf(tmax, __shfl_xor(tmax, 1));
                    tmax = fmaxf(tmax, __shfl_xor(tmax, 2));
                    tmax = fmaxf(tmax, __shfl_xor(tmax, 4));
                    tmax = fmaxf(tmax, __shfl_xor(tmax, 8));
                    float mo = mrow[mf][r];
                    float mn = fmaxf(mo, tmax);
                    float fs = __expf(mo - mn);
                    mrow[mf][r] = mn;
                    float ps = 0.f;
#pragma unroll
                    for (int n = 0; n < 4; n++) {
                        float p = __expf(sc[n][r] - mn);
                        sc[n][r] = p;
                        ps += p;
                    }
                    ps += __shfl_xor(ps, 1);
                    ps += __shfl_xor(ps, 2);
                    ps += __shfl_xor(ps, 4);
                    ps += __shfl_xor(ps, 8);
                    srow[mf][r] = srow[mf][r] * fs + ps;
#pragma unroll
                    for (int n = 0; n < 4; n++) o[mf][n][r] *= fs;
                }
#pragma unroll
                for (int r = 0; r < 4; r++) {
                    int prow = 32 * w + 16 * mf + 4 * g + r;
                    char* pb = PsB + prow * 128;
                    int sz = (prow & 7) << 4;
#pragma unroll
                    for (int n = 0; n < 4; n++)
                        *reinterpret_cast<__hip_bfloat16*>(pb + (((16 * n + lr) * 2) ^ sz)) =
                            __float2bfloat16(sc[n][r]);
                }
            }
            bx8 vb[4][2];
#pragma unroll
            for (int n = 0; n < 4; n++)
#pragma unroll
                for (int ks = 0; ks < 2; ks++) {
                    int row = 16 * n + lr;
                    vb[n][ks] = *reinterpret_cast<const bx8*>(
                        VsB + row * 128 + (((ks * 64) + 16 * g) ^ ((row & 7) << 4)));
                }
#pragma unroll
            for (int mf = 0; mf < 2; mf++) {
                bx8 pa[2];
#pragma unroll
                for (int ks = 0; ks < 2; ks++) {
                    int prow = 32 * w + 16 * mf + lr;
                    pa[ks] = *reinterpret_cast<const bx8*>(
                        PsB + prow * 128 + (((ks * 64) + 16 * g) ^ ((prow & 7) << 4)));
                }
#pragma unroll
                for (int n = 0; n < 4; n++) {
                    o[mf][n] = __builtin_amdgcn_mfma_f32_16x16x32_bf16(pa[0], vb[n][0], o[mf][n], 0, 0, 0);
                    o[mf][n] = __builtin_amdgcn_mfma_f32_16x16x32_bf16(pa[1], vb[n][1], o[mf][n], 0, 0, 0);
                }
            }
        }
        __syncthreads();
    }

#pragma unroll
    for (int mf = 0; mf < 2; mf++) {
        float inv[4];
#pragma unroll
        for (int r = 0; r < 4; r++) inv[r] = 1.f / srow[mf][r];
#pragma unroll
        for (int n = 0; n < 4; n++)
#pragma unroll
            for (int r = 0; r < 4; r++) {
                int rq = qbw + 16 * mf + 4 * g + r;
                O[(size_t)rq * HID + h * HD + 16 * n + lr] = __float2bfloat16(o[mf][n][r] * inv[r]);
            }
    }
}

extern "C" void kernel_launch(void* const* d_in, const int* in_sizes, int n_in,
                              void* d_out, int out_size, void* d_ws, size_t ws_size,
                              hipStream_t stream) {
    const float* hs = (const float*)d_in[0];
    const float* Wq = (const float*)d_in[1];
    const float* Wk = (const float*)d_in[2];
    const float* Wv = (const float*)d_in[3];
    const float* Wo = (const float*)d_in[4];

    float* ws   = (float*)d_ws;
    float* cosT = ws;                  // 65536 f32
    float* sinT = cosT + 65536;        // 65536 f32
    __hip_bfloat16* hsb    = (__hip_bfloat16*)(sinT + 65536);   // [2048][2048]
    __hip_bfloat16* WqkvT  = hsb + 4194304;                     // [3072][2048]: Wq|Wk|Wv rows
    __hip_bfloat16* WoT    = WqkvT + 6291456;                   // [2048][2048]
    __hip_bfloat16* QKVb   = WoT + 4194304;                     // [2048][3072]
    __hip_bfloat16* Vt     = QKVb + 6291456;                    // [512][2048]
    __hip_bfloat16* Ab     = hsb;                               // alias: hsb dead after QKV gemm

    rope_table_kernel<<<(S_LEN * 32) / 256, 256, 0, stream>>>(cosT, sinT);
    conv_kernel<<<2048, 256, 0, stream>>>(hs, hsb);
    convT_kernel<<<dim3(64, 64), dim3(32, 8), 0, stream>>>(Wq, WqkvT, 2048, 2048, 2048);
    convT_kernel<<<dim3(16, 64), dim3(32, 8), 0, stream>>>(Wk, WqkvT + (size_t)2048 * 2048, 2048, 512, 2048);
    convT_kernel<<<dim3(16, 64), dim3(32, 8), 0, stream>>>(Wv, WqkvT + (size_t)2560 * 2048, 2048, 512, 2048);
    convT_kernel<<<dim3(64, 64), dim3(32, 8), 0, stream>>>(Wo, WoT, 2048, 2048, 2048);

    // fused QKV projection: [2048][3072] = hsb @ WqkvT^T   (384 blocks, nbx=24)
    gemm_pipe_kernel<1><<<384, 256, 0, stream>>>(hsb, WqkvT, QKVb, 2048, QKVN, 2048, 24);

    rope_kernel<<<(S_LEN * (NH + NKV) * 32) / 256, 256, 0, stream>>>(QKVb, cosT, sinT);

    vtrans_kernel<<<dim3(64, 16), dim3(32, 8), 0, stream>>>(QKVb, Vt);

    attn_kernel<<<512, 256, 0, stream>>>(QKVb, QKVb + 2048, Vt, Ab);

    // output projection: d_out = Ab @ WoT^T   (256 blocks, nbx=16)
    gemm_pipe_kernel<0><<<256, 256, 0, stream>>>(Ab, WoT, d_out, 2048, 2048, 2048, 16);
}